// Round 7
// baseline (479.446 us; speedup 1.0000x reference)
//
#include <hip/hip_runtime.h>
#include <hip/hip_bf16.h>
#include <stdint.h>

typedef __bf16 bf16;
typedef __bf16 bf16x2 __attribute__((ext_vector_type(2)));
typedef __bf16 bf16x4 __attribute__((ext_vector_type(4)));
typedef __bf16 bf16x8 __attribute__((ext_vector_type(8)));
typedef float f32x4 __attribute__((ext_vector_type(4)));

#define AS1 __attribute__((address_space(1)))
#define AS3 __attribute__((address_space(3)))

static __device__ __forceinline__ void async_cp16(const bf16* g, bf16* l) {
    __builtin_amdgcn_global_load_lds((const AS1 void*)g, (AS3 void*)l, 16, 0, 0);
}

static __device__ __forceinline__ bf16x4 cvt4(f32x4 v) {
    bf16x4 r;
    r[0] = (bf16)v[0]; r[1] = (bf16)v[1]; r[2] = (bf16)v[2]; r[3] = (bf16)v[3];
    return r;
}

static __device__ __forceinline__ float fast_exp2(float x) {
#if __has_builtin(__builtin_amdgcn_exp2f)
    return __builtin_amdgcn_exp2f(x);
#else
    return __expf(x * 0.69314718056f);
#endif
}

// ---------------------------------------------------------------------------
// prep_kernel: fused {Kone one-hot build + slack zeroing} + fp32->bf16 bulk
// convert of hs/qkv_w/proj_w (dsts contiguous in ws). One dispatch instead of
// two (~10 us of launch gap per dispatch at this problem size).
__global__ __launch_bounds__(256) void prep_kernel(
    const float* __restrict__ hs, const float* __restrict__ qw,
    const float* __restrict__ pw, bf16* __restrict__ dst,
    bf16* __restrict__ Kone, bf16* __restrict__ slackA, bf16* __restrict__ slackB) {
    const int gid = blockIdx.x * 256 + threadIdx.x;
    // part 1: Kone [1600][32]: dim j<28: j==27-wk; dim 28+jj: jj==3-(hk-ha)
    if (gid < 6400) {
        const int key = gid >> 2, chunk = gid & 3;
        const int hk = key / 28;
        const int wk = key - hk * 28;
        const int kt = key >> 6;
        const int ha = (kt << 6) / 28;
        const int jw = 27 - wk;
        const int jh = 31 - (hk - ha);
        bf16x8 v;
#pragma unroll
        for (int e = 0; e < 8; e++) {
            const int j = chunk * 8 + e;
            v[e] = (j == jw || j == jh) ? (bf16)1.0f : (bf16)0.0f;
        }
        *(bf16x8*)&Kone[key * 32 + chunk * 8] = v;
    } else if (gid < 6656) {
        const int i = gid - 6400;   // 2048 slack elems after Kb and Vt
        bf16x8 z = {};
        *(bf16x8*)&slackA[i * 8] = z;
        *(bf16x8*)&slackB[i * 8] = z;
    }
    // part 2: grid-stride cvt
    const int H4 = 6272 * 1024 / 4, Q4 = 3072 * 1024 / 4, P4 = 1024 * 1024 / 4;
    const int total = H4 + Q4 + P4;
    const int stride = gridDim.x * 256;
    for (int i = gid; i < total; i += stride) {
        f32x4 v;
        if (i < H4)            v = ((const f32x4*)hs)[i];
        else if (i < H4 + Q4)  v = ((const f32x4*)qw)[i - H4];
        else                   v = ((const f32x4*)pw)[i - H4 - Q4];
        ((bf16x4*)dst)[i] = cvt4(v);
    }
}

// setup-only kernel for the f32 fallback path (no cvt needed there).
__global__ __launch_bounds__(256) void setup_misc(
    bf16* __restrict__ Kone, bf16* __restrict__ slackA, bf16* __restrict__ slackB) {
    const int idx = blockIdx.x * 256 + threadIdx.x;
    if (idx < 6400) {
        const int key = idx >> 2, chunk = idx & 3;
        const int hk = key / 28;
        const int wk = key - hk * 28;
        const int kt = key >> 6;
        const int ha = (kt << 6) / 28;
        const int jw = 27 - wk;
        const int jh = 31 - (hk - ha);
        bf16x8 v;
#pragma unroll
        for (int e = 0; e < 8; e++) {
            const int j = chunk * 8 + e;
            v[e] = (j == jw || j == jh) ? (bf16)1.0f : (bf16)0.0f;
        }
        *(bf16x8*)&Kone[key * 32 + chunk * 8] = v;
    } else if (idx < 6656) {
        const int i = idx - 6400;
        bf16x8 z = {};
        *(bf16x8*)&slackA[i * 8] = z;
        *(bf16x8*)&slackB[i * 8] = z;
    }
}

// NOTE: epilogue is INLINED in both qkv kernels. An earlier round passed
// acc[4][4] into a helper; array-decay defeated SROA -> acc lived in scratch.
// Do not refactor accumulators through pointers.
//
// Q is pre-scaled by C2 = 0.125*log2(e) here so flash_attn's QK MFMA output
// is already in the exp2 domain (the rel-pos tables compensate with *8).

#define QKV_EPILOGUE()                                                        \
    for (int nt = 0; nt < 4; nt++) {                                          \
        const int n_ = n0 + wn + nt * 16 + lm;                                \
        const float bv = bias[n_];                                            \
        const int s = n_ >> 10, rem = n_ & 1023;                              \
        const int h = rem >> 6, d = rem & 63;                                 \
        const float qsc = (s == 0) ? 0.18033688011112042f : 1.0f;             \
        for (int mt = 0; mt < 4; mt++) {                                      \
            for (int r = 0; r < 4; r++) {                                     \
                const int m_ = m0 + wm + mt * 16 + quad * 4 + r;              \
                const int b = m_ / 1568;                                      \
                const int pix = m_ - b * 1568;                                \
                const int g = b * 16 + h;                                     \
                const bf16 v = (bf16)((acc[mt][nt][r] + bv) * qsc);           \
                if (s == 0)      Qb[((size_t)g * 1568 + pix) * 64 + d] = v;   \
                else if (s == 1) Kb[((size_t)g * 1568 + pix) * 64 + d] = v;   \
                else {                                                        \
                    const int lk = pix & 31;                                  \
                    const int ppix = (pix & ~31) | ((lk & 15) << 1) | (lk >> 4); \
                    Vt[((size_t)g * 64 + d) * 1568 + ppix] = v;               \
                }                                                             \
            }                                                                 \
        }                                                                     \
    }

// Round-5 proven structure: 2-buffer dbuf, __syncthreads per tile. Latency
// hiding here comes from BLOCK-level TLP (round-6 lesson: trading LDS for
// pipeline depth regressed 28%). __launch_bounds__(256,5) caps VGPR at ~102
// so LDS (32KB -> 5 blocks/CU) becomes the binding limit instead of VGPR
// (112 -> 4 blocks/CU in round 5): +25% co-resident blocks.

// ---------------------------------------------------------------------------
// Kernel 1a: QKV projection, bf16 inputs, XCD-chunked swizzle (1176 blocks).
__global__ __launch_bounds__(256, 5) void qkv_gemm_bf16(
    const bf16* __restrict__ A, const bf16* __restrict__ W,
    const float* __restrict__ bias, bf16* __restrict__ Qb,
    bf16* __restrict__ Kb, bf16* __restrict__ Vt) {
    __shared__ bf16 As[2][128 * 32];
    __shared__ bf16 Bs[2][128 * 32];
    const int t = threadIdx.x;
    const int wid = t >> 6, lane = t & 63;
    const int bid = blockIdx.x;
    const int widx = (bid & 7) * 147 + (bid >> 3);
    const int mt_ = widx / 24;
    const int m0 = mt_ * 128, n0 = (widx - mt_ * 24) * 128;
    const int wm = (wid & 1) * 64, wn = (wid >> 1) * 64;
    const int r_i = lane >> 2, c8 = (lane & 3) * 8;
    const int lm = lane & 15, quad = lane >> 4;

#define QKV_STAGE(buf, kk)                                                     \
    for (int i = 0; i < 2; i++) {                                              \
        const int blk = wid * 2 + i;                                           \
        async_cp16(A + (size_t)(m0 + blk * 16 + r_i) * 1024 + (kk) + c8,       \
                   &As[buf][blk * 512]);                                       \
        async_cp16(W + (size_t)(n0 + blk * 16 + r_i) * 1024 + (kk) + c8,       \
                   &Bs[buf][blk * 512]);                                       \
    }

    f32x4 acc[4][4] = {};
    QKV_STAGE(0, 0)
    __syncthreads();
    int cur = 0;
    for (int k0 = 0; k0 < 1024; k0 += 32) {
        if (k0 < 992) { QKV_STAGE(cur ^ 1, k0 + 32) }
        bf16x8 af[4], bfr[4];
        for (int x = 0; x < 4; x++) {
            af[x]  = *(const bf16x8*)&As[cur][(wm + x * 16 + lm) * 32 + quad * 8];
            bfr[x] = *(const bf16x8*)&Bs[cur][(wn + x * 16 + lm) * 32 + quad * 8];
        }
        for (int mt = 0; mt < 4; mt++)
            for (int nt = 0; nt < 4; nt++)
                acc[mt][nt] = __builtin_amdgcn_mfma_f32_16x16x32_bf16(af[mt], bfr[nt], acc[mt][nt], 0, 0, 0);
        __syncthreads();
        cur ^= 1;
    }
#undef QKV_STAGE
    QKV_EPILOGUE()
}

// Kernel 1b: fallback — fp32 inputs, convert at LDS-stage time (dbuf).
__global__ __launch_bounds__(256) void qkv_gemm_f32(
    const float* __restrict__ A, const float* __restrict__ W,
    const float* __restrict__ bias, bf16* __restrict__ Qb,
    bf16* __restrict__ Kb, bf16* __restrict__ Vt) {
    __shared__ bf16 As[2][128 * 32];
    __shared__ bf16 Bs[2][128 * 32];
    const int t = threadIdx.x;
    const int wid = t >> 6, lane = t & 63;
    const int bid = blockIdx.x;
    const int widx = (bid & 7) * 147 + (bid >> 3);
    const int mt_ = widx / 24;
    const int m0 = mt_ * 128, n0 = (widx - mt_ * 24) * 128;
    const int wm = (wid & 1) * 64, wn = (wid >> 1) * 64;
    const int lm = lane & 15, quad = lane >> 4;

#define QKVF_STAGE(buf, kk)                                                    \
    for (int i = 0; i < 4; i++) {                                              \
        const int idx = t + i * 256;                                           \
        const int row = idx >> 3, c4 = (idx & 7) * 4;                          \
        const f32x4 av = *(const f32x4*)&A[(size_t)(m0 + row) * 1024 + (kk) + c4]; \
        const f32x4 wv = *(const f32x4*)&W[(size_t)(n0 + row) * 1024 + (kk) + c4]; \
        *(bf16x4*)&As[buf][row * 32 + c4] = cvt4(av);                          \
        *(bf16x4*)&Bs[buf][row * 32 + c4] = cvt4(wv);                          \
    }

    f32x4 acc[4][4] = {};
    QKVF_STAGE(0, 0)
    __syncthreads();
    int cur = 0;
    for (int k0 = 0; k0 < 1024; k0 += 32) {
        if (k0 < 992) { QKVF_STAGE(cur ^ 1, k0 + 32) }
        bf16x8 af[4], bfr[4];
        for (int x = 0; x < 4; x++) {
            af[x]  = *(const bf16x8*)&As[cur][(wm + x * 16 + lm) * 32 + quad * 8];
            bfr[x] = *(const bf16x8*)&Bs[cur][(wn + x * 16 + lm) * 32 + quad * 8];
        }
        for (int mt = 0; mt < 4; mt++)
            for (int nt = 0; nt < 4; nt++)
                acc[mt][nt] = __builtin_amdgcn_mfma_f32_16x16x32_bf16(af[mt], bfr[nt], acc[mt][nt], 0, 0, 0);
        __syncthreads();
        cur ^= 1;
    }
#undef QKVF_STAGE
    QKV_EPILOGUE()
}

// ---------------------------------------------------------------------------
// Kernel 2: flash attention, KVBLK=64, 25 tiles, ONE barrier per tile.
// (unchanged — staging latency is covered by the tile's own QK+softmax+PV)
__global__ __launch_bounds__(256) void flash_attn(
    const bf16* __restrict__ Qb, const bf16* __restrict__ Kb,
    const bf16* __restrict__ Vt, const float* __restrict__ rph,
    const float* __restrict__ rpw, const bf16* __restrict__ Kone,
    bf16* __restrict__ AO) {
    const int x = blockIdx.x;
    const int xcd = x & 7, j = x >> 3;          // j in 0..199
    const int g = xcd * 8 + j / 25;
    const int qblk = j - (j / 25) * 25;
    const int q0 = qblk * 64;
    const int hqb = q0 / 28;                    // first image row of this block

    __shared__ __align__(16) char smem[51200];
    bf16* Th = (bf16*)smem;
    const char* ThC = (const char*)smem;
    char* B = smem + 8192;
    bf16* Qs  = (bf16*)(B + 32768);
    bf16* RPh = (bf16*)(B + 0);
    bf16* RPw = (bf16*)(B + 9216);
    float* TwF = (float*)(B + 18432);
    bf16* TwS = (bf16*)(B + 33280);

    const int t = threadIdx.x, wid = t >> 6, lane = t & 63;
    const int lm = lane & 15, quad = lane >> 4;
    const int qbase_l = wid * 16 + quad * 4;
    const int swz = (lm & 7) << 4;
    const int l3 = lane >> 3, l7 = lane & 7;
    const int swe = ((l7 ^ l3) << 3);           // pre-swizzled source col (elems)

    const bf16* kSrc[2];
    const bf16* vSrc[2];
#pragma unroll
    for (int i = 0; i < 2; i++) {
        kSrc[i] = Kb + ((size_t)g * 1568 + wid * 16 + i * 8 + l3) * 64 + swe;
        vSrc[i] = Vt + ((size_t)g * 64 + wid * 16 + i * 8 + l3) * 1568 + swe;
    }

    // phase 0: stage Q tile (rows clamped for the q tail) + rph
    for (int c = t; c < 512; c += 256) {
        const int row = c >> 3, col = (c & 7) * 8;
        const int qg = min(q0 + row, 1567);
        *(bf16x8*)&Qs[row * 72 + col] =
            *(const bf16x8*)&Qb[((size_t)g * 1568 + qg) * 64 + col];
    }
    for (int c = t; c < 1024; c += 256) {
        const int row = c >> 4, col = (c & 15) * 4;
        const int rg = min(hqb + row, 110);
        *(bf16x4*)&RPh[row * 72 + col] = cvt4(*(const f32x4*)&rph[rg * 64 + col]);
    }
    __syncthreads();

    // phase 1: qf reads, Th MFMA (reads RPh), stage rpw (disjoint region)
    const int qrow_l = wid * 16 + lm;
    const bf16x8 qf0 = *(const bf16x8*)&Qs[qrow_l * 72 + quad * 8];
    const bf16x8 qf1 = *(const bf16x8*)&Qs[qrow_l * 72 + 32 + quad * 8];
    const int qgl = min(q0 + qrow_l, 1567);
    const int thb2 = (qrow_l * 64 + (qgl / 28 - hqb) + 54) * 2;   // byte base

    for (int c = t; c < 1024; c += 256) {
        const int row = c >> 4, col = (c & 15) * 4;
        const int rg = min(row, 54);
        *(bf16x4*)&RPw[row * 72 + col] = cvt4(*(const f32x4*)&rpw[rg * 64 + col]);
    }
    f32x4 acch[4];
#pragma unroll
    for (int nt = 0; nt < 4; nt++) {
        const bf16x8 b0 = *(const bf16x8*)&RPh[(nt * 16 + lm) * 72 + quad * 8];
        const bf16x8 b1 = *(const bf16x8*)&RPh[(nt * 16 + lm) * 72 + 32 + quad * 8];
        f32x4 a = {};
        a = __builtin_amdgcn_mfma_f32_16x16x32_bf16(qf0, b0, a, 0, 0, 0);
        a = __builtin_amdgcn_mfma_f32_16x16x32_bf16(qf1, b1, a, 0, 0, 0);
        acch[nt] = a;
    }
    __syncthreads();

    // phase 2: write Th (bf16, *8, col+2 shift, cols 0..1 zeroed),
    //          Tw MFMA (reads RPw) -> TwF f32
#pragma unroll
    for (int nt = 0; nt < 4; nt++) {
        const int c = nt * 16 + lm;
        if (c < 59) {
#pragma unroll
            for (int r = 0; r < 4; r++)
                Th[(qbase_l + r) * 64 + c + 2] = (bf16)(acch[nt][r] * 8.0f);
        }
    }
    if (lm == 0) {
#pragma unroll
        for (int r = 0; r < 4; r++) {
            Th[(qbase_l + r) * 64 + 0] = (bf16)0.0f;
            Th[(qbase_l + r) * 64 + 1] = (bf16)0.0f;
        }
    }
#pragma unroll
    for (int nt = 0; nt < 4; nt++) {
        const bf16x8 b0 = *(const bf16x8*)&RPw[(nt * 16 + lm) * 72 + quad * 8];
        const bf16x8 b1 = *(const bf16x8*)&RPw[(nt * 16 + lm) * 72 + 32 + quad * 8];
        f32x4 a = {};
        a = __builtin_amdgcn_mfma_f32_16x16x32_bf16(qf0, b0, a, 0, 0, 0);
        a = __builtin_amdgcn_mfma_f32_16x16x32_bf16(qf1, b1, a, 0, 0, 0);
        const int c = nt * 16 + lm;
        if (c < 55) {
#pragma unroll
            for (int r = 0; r < 4; r++)
                TwF[(qbase_l + r) * 58 + c] = a[r] * 8.0f;
        }
    }
    __syncthreads();

    // phase 3: build TwS [64][32] bf16 (per-q-row shifted Tw window)
    {
        const int row = t >> 2, chunk = t & 3;
        const int qg = min(q0 + row, 1567);
        const int wq = qg % 28;
        const float* src = &TwF[row * 58 + wq];
        bf16x8 v;
        if (chunk < 3) {
#pragma unroll
            for (int e = 0; e < 8; e++) v[e] = (bf16)src[chunk * 8 + e];
        } else {
#pragma unroll
            for (int e = 0; e < 4; e++) v[e] = (bf16)src[24 + e];
#pragma unroll
            for (int e = 4; e < 8; e++) v[e] = (bf16)0.0f;
        }
        *(bf16x8*)&TwS[row * 32 + chunk * 8] = v;
    }
    __syncthreads();                             // barrier A

    const bf16x8 qt_mine = *(const bf16x8*)&TwS[qrow_l * 32 + quad * 8];

    // stage tile 0 (async, swizzled source) + load Kone tile 0 into regs
#pragma unroll
    for (int i = 0; i < 2; i++) {
        async_cp16(kSrc[i], (bf16*)(B + (wid * 2 + i) * 1024));
        async_cp16(vSrc[i], (bf16*)(B + 16384 + (wid * 2 + i) * 1024));
        kSrc[i] += 4096;
        vSrc[i] += 64;
    }
    const bf16* kop = Kone + lm * 32 + quad * 8;
    bf16x8 ko[4];
#pragma unroll
    for (int f = 0; f < 4; f++) ko[f] = *(const bf16x8*)(kop + f * 512);
    __syncthreads();                             // barrier B (drains staging)

    f32x4 o[4] = {};
    f32x4 lsum = {};
    const f32x4 zero4 = {};
    bf16x8 ones;
#pragma unroll
    for (int i = 0; i < 8; i++) ones[i] = (bf16)1.0f;

    bf16* P0w = (bf16*)(B + 32768) + wid * 640;
    bf16* P1w = (bf16*)(B + 37888) + wid * 640;

    int curo = 0;
    for (int kt = 0; kt < 25; kt++) {
        // Q' quad3 refresh: 4-value Th window (bf16, wave-own rows)
        bf16x8 qf2 = qt_mine;
        if (quad == 3) {
            const int ha = (kt << 6) / 28;
            const char* tp = ThC + (thb2 - (ha << 1));
            qf2[4] = *(const bf16*)(tp);
            qf2[5] = *(const bf16*)(tp + 2);
            qf2[6] = *(const bf16*)(tp + 4);
            qf2[7] = *(const bf16*)(tp + 6);
        }

        // stage tile kt+1 into buf[cur^1] (async; sources pre-swizzled)
        if (kt < 24) {
            const int nxto = curo ^ 8192;
#pragma unroll
            for (int i = 0; i < 2; i++) {
                async_cp16(kSrc[i], (bf16*)(B + nxto + (wid * 2 + i) * 1024));
                async_cp16(vSrc[i], (bf16*)(B + 16384 + nxto + (wid * 2 + i) * 1024));
                kSrc[i] += 4096;
                vSrc[i] += 64;
            }
        }

        // S = bias (one-hot MFMA, C=0) + QK^T
        __builtin_amdgcn_s_setprio(1);
        f32x4 s[4];
#pragma unroll
        for (int f = 0; f < 4; f++)
            s[f] = __builtin_amdgcn_mfma_f32_16x16x32_bf16(qf2, ko[f], zero4, 0, 0, 0);
        {
            const char* KsB = B + curo;
            const int x0 = (quad * 16) ^ swz;
#pragma unroll
            for (int f = 0; f < 4; f++) {
                const char* rp = KsB + (f * 16 + lm) * 128;
                const bf16x8 ka = *(const bf16x8*)(rp + x0);
                const bf16x8 kb2 = *(const bf16x8*)(rp + (x0 ^ 64));
                s[f] = __builtin_amdgcn_mfma_f32_16x16x32_bf16(qf0, ka, s[f], 0, 0, 0);
                s[f] = __builtin_amdgcn_mfma_f32_16x16x32_bf16(qf1, kb2, s[f], 0, 0, 0);
            }
        }
        __builtin_amdgcn_s_setprio(0);

        // reload Kone fragments for the next tile (L1-hot, a whole PV of cover)
        if (kt < 24) {
            kop += 2048;
#pragma unroll
            for (int f = 0; f < 4; f++) ko[f] = *(const bf16x8*)(kop + f * 512);
        }

        if (kt == 24) {                          // keys >= 1568: p == 0
#pragma unroll
            for (int r = 0; r < 4; r++) { s[2][r] = -30000.0f; s[3][r] = -30000.0f; }
        }

        // exp2 + both P halves written, ONE wait, then lsum + PV
#pragma unroll
        for (int r = 0; r < 4; r++) {
            const float a0 = fast_exp2(s[0][r]);
            const float a1 = fast_exp2(s[1][r]);
            bf16x2 pp; pp[0] = (bf16)a0; pp[1] = (bf16)a1;
            *(bf16x2*)&P0w[(quad * 4 + r) * 40 + lm * 2] = pp;
            const float b0 = fast_exp2(s[2][r]);
            const float b1 = fast_exp2(s[3][r]);
            bf16x2 qq; qq[0] = (bf16)b0; qq[1] = (bf16)b1;
            *(bf16x2*)&P1w[(quad * 4 + r) * 40 + lm * 2] = qq;
        }
        __asm__ volatile("s_waitcnt lgkmcnt(0)" ::: "memory");
        const bf16x8 pf0 = *(const bf16x8*)&P0w[lm * 40 + quad * 8];
        const bf16x8 pf1 = *(const bf16x8*)&P1w[lm * 40 + quad * 8];
        lsum = __builtin_amdgcn_mfma_f32_16x16x32_bf16(pf0, ones, lsum, 0, 0, 0);
        lsum = __builtin_amdgcn_mfma_f32_16x16x32_bf16(pf1, ones, lsum, 0, 0, 0);
        __builtin_amdgcn_s_setprio(1);
        {
            const char* VsB = B + 16384 + curo;
#pragma unroll
            for (int dt = 0; dt < 4; dt++) {
                const bf16x8 vf = *(const bf16x8*)(VsB + (dt * 16 + lm) * 128 +
                                                   ((quad * 16) ^ swz));
                o[dt] = __builtin_amdgcn_mfma_f32_16x16x32_bf16(pf0, vf, o[dt], 0, 0, 0);
            }
#pragma unroll
            for (int dt = 0; dt < 4; dt++) {
                const bf16x8 vf = *(const bf16x8*)(VsB + (dt * 16 + lm) * 128 +
                                                   ((64 + quad * 16) ^ swz));
                o[dt] = __builtin_amdgcn_mfma_f32_16x16x32_bf16(pf1, vf, o[dt], 0, 0, 0);
            }
        }
        __builtin_amdgcn_s_setprio(0);

        if (kt < 24) {                           // uniform: one barrier per tile
            __syncthreads();
            curo ^= 8192;
        }
    }

    // epilogue: lsum already holds per-row softmax denominators (no shuffle)
    if (q0 + wid * 16 < 1568) {
        const int bo = g >> 4, hh = g & 15;
#pragma unroll
        for (int r = 0; r < 4; r++) {
            const float inv = 1.0f / lsum[r];
            const size_t base = ((size_t)bo * 1568 + q0 + qbase_l + r) * 1024 + hh * 64;
#pragma unroll
            for (int dt = 0; dt < 4; dt++)
                AO[base + dt * 16 + lm] = (bf16)(o[dt][r] * inv);
        }
    }
}

// ---------------------------------------------------------------------------
// Kernel 3a: output projection, bf16 operands, XCD swizzle, dbuf K-loop.
__global__ __launch_bounds__(256, 5) void proj_gemm_bf16(
    const bf16* __restrict__ A, const bf16* __restrict__ W,
    const float* __restrict__ bias, float* __restrict__ out) {
    __shared__ bf16 As[2][128 * 32];
    __shared__ bf16 Bs[2][128 * 32];
    const int t = threadIdx.x;
    const int wid = t >> 6, lane = t & 63;
    const int bid = blockIdx.x;
    const int widx = (bid & 7) * 49 + (bid >> 3);
    const int m0 = (widx >> 3) * 128, n0 = (widx & 7) * 128;
    const int wm = (wid & 1) * 64, wn = (wid >> 1) * 64;
    const int r_i = lane >> 2, c8 = (lane & 3) * 8;
    const int lm = lane & 15, quad = lane >> 4;

#define PROJ_STAGE(buf, kk)                                                    \
    for (int i = 0; i < 2; i++) {                                              \
        const int blk = wid * 2 + i;                                           \
        async_cp16(A + (size_t)(m0 + blk * 16 + r_i) * 1024 + (kk) + c8,       \
                   &As[buf][blk * 512]);                                       \
        async_cp16(W + (size_t)(n0 + blk * 16 + r_i) * 1024 + (kk) + c8,       \
                   &Bs[buf][blk * 512]);                                       \
    }

    f32x4 acc[4][4] = {};
    PROJ_STAGE(0, 0)
    __syncthreads();
    int cur = 0;
    for (int k0 = 0; k0 < 1024; k0 += 32) {
        if (k0 < 992) { PROJ_STAGE(cur ^ 1, k0 + 32) }
        bf16x8 af[4], bfr[4];
        for (int x = 0; x < 4; x++) {
            af[x]  = *(const bf16x8*)&As[cur][(wm + x * 16 + lm) * 32 + quad * 8];
            bfr[x] = *(const bf16x8*)&Bs[cur][(wn + x * 16 + lm) * 32 + quad * 8];
        }
        for (int mt = 0; mt < 4; mt++)
            for (int nt = 0; nt < 4; nt++)
                acc[mt][nt] = __builtin_amdgcn_mfma_f32_16x16x32_bf16(af[mt], bfr[nt], acc[mt][nt], 0, 0, 0);
        __syncthreads();
        cur ^= 1;
    }
#undef PROJ_STAGE
    for (int nt = 0; nt < 4; nt++) {
        const int n_ = n0 + wn + nt * 16 + lm;
        const float bv = bias[n_];
        for (int mt = 0; mt < 4; mt++)
            for (int r = 0; r < 4; r++) {
                const int m_ = m0 + wm + mt * 16 + quad * 4 + r;
                out[(size_t)m_ * 1024 + n_] = acc[mt][nt][r] + bv;
            }
    }
}

// Kernel 3b: fallback — W fp32, converted at stage time (dbuf).
__global__ __launch_bounds__(256) void proj_gemm_f32(
    const bf16* __restrict__ A, const float* __restrict__ W,
    const float* __restrict__ bias, float* __restrict__ out) {
    __shared__ bf16 As[2][128 * 32];
    __shared__ bf16 Bs[2][128 * 32];
    const int t = threadIdx.x;
    const int wid = t >> 6, lane = t & 63;
    const int bid = blockIdx.x;
    const int widx = (bid & 7) * 49 + (bid >> 3);
    const int m0 = (widx >> 3) * 128, n0 = (widx & 7) * 128;
    const int wm = (wid & 1) * 64, wn = (wid >> 1) * 64;
    const int r_i = lane >> 2, c8 = (lane & 3) * 8;
    const int lm = lane & 15, quad = lane >> 4;

#define PROJF_STAGE(buf, kk)                                                   \
    for (int i = 0; i < 2; i++) {                                              \
        const int blk = wid * 2 + i;                                           \
        async_cp16(A + (size_t)(m0 + blk * 16 + r_i) * 1024 + (kk) + c8,       \
                   &As[buf][blk * 512]);                                       \
    }                                                                          \
    for (int i = 0; i < 4; i++) {                                              \
        const int idx = t + i * 256;                                           \
        const int row = idx >> 3, c4 = (idx & 7) * 4;                          \
        const f32x4 wv = *(const f32x4*)&W[(size_t)(n0 + row) * 1024 + (kk) + c4]; \
        *(bf16x4*)&Bs[buf][row * 32 + c4] = cvt4(wv);                          \
    }

    f32x4 acc[4][4] = {};
    PROJF_STAGE(0, 0)
    __syncthreads();
    int cur = 0;
    for (int k0 = 0; k0 < 1024; k0 += 32) {
        if (k0 < 992) { PROJF_STAGE(cur ^ 1, k0 + 32) }
        bf16x8 af[4], bfr[4];
        for (int x = 0; x < 4; x++) {
            af[x]  = *(const bf16x8*)&As[cur][(wm + x * 16 + lm) * 32 + quad * 8];
            bfr[x] = *(const bf16x8*)&Bs[cur][(wn + x * 16 + lm) * 32 + quad * 8];
        }
        for (int mt = 0; mt < 4; mt++)
            for (int nt = 0; nt < 4; nt++)
                acc[mt][nt] = __builtin_amdgcn_mfma_f32_16x16x32_bf16(af[mt], bfr[nt], acc[mt][nt], 0, 0, 0);
        __syncthreads();
        cur ^= 1;
    }
#undef PROJF_STAGE
    for (int nt = 0; nt < 4; nt++) {
        const int n_ = n0 + wn + nt * 16 + lm;
        const float bv = bias[n_];
        for (int mt = 0; mt < 4; mt++)
            for (int r = 0; r < 4; r++) {
                const int m_ = m0 + wm + mt * 16 + quad * 4 + r;
                out[(size_t)m_ * 1024 + n_] = acc[mt][nt][r] + bv;
            }
    }
}

// ---------------------------------------------------------------------------
extern "C" void kernel_launch(void* const* d_in, const int* in_sizes, int n_in,
                              void* d_out, int out_size, void* d_ws, size_t ws_size,
                              hipStream_t stream) {
    const float* hs     = (const float*)d_in[0];
    const float* qkv_w  = (const float*)d_in[1];
    const float* qkv_b  = (const float*)d_in[2];
    const float* proj_w = (const float*)d_in[3];
    const float* proj_b = (const float*)d_in[4];
    const float* rph    = (const float*)d_in[5];
    const float* rpw    = (const float*)d_in[6];
    float* out = (float*)d_out;

    const size_t GQ  = (size_t)64 * 1568 * 64; // elems per Q/K/V/AO
    const size_t SL  = 2048;                   // slack after Kb and Vt
    const size_t N_KONE = (size_t)1600 * 32;
    const size_t N_HS = (size_t)6272 * 1024;
    const size_t N_QW = (size_t)3072 * 1024;
    const size_t N_PW = (size_t)1024 * 1024;
    bf16* Qb = (bf16*)d_ws;                    // [g][1568][64] (pre-scaled by C2)
    bf16* Kb = Qb + GQ;                        // [g][1568][64] + slack
    bf16* Vt = Kb + GQ + SL;                   // [g][64][1568] (permuted) + slack
    bf16* AO = Vt + GQ + SL;                   // [6272][1024]
    bf16* Kone = AO + GQ;                      // [1600][32] one-hot
    bf16* hs_bf    = Kone + N_KONE;            // hs_bf/qkvw_bf/projw_bf contiguous
    bf16* qkvw_bf  = hs_bf + N_HS;
    bf16* projw_bf = qkvw_bf + N_QW;
    const size_t need = (4 * GQ + 2 * SL + N_KONE + N_HS + N_QW + N_PW) * sizeof(bf16);

    if (ws_size >= need) {
        prep_kernel<<<1024, 256, 0, stream>>>(hs, qkv_w, proj_w, hs_bf,
                                              Kone, Kb + GQ, Vt + GQ);
        qkv_gemm_bf16<<<1176, 256, 0, stream>>>(hs_bf, qkvw_bf, qkv_b, Qb, Kb, Vt);
        flash_attn<<<1600, 256, 0, stream>>>(Qb, Kb, Vt, rph, rpw, Kone, AO);
        proj_gemm_bf16<<<392, 256, 0, stream>>>(AO, projw_bf, proj_b, out);
    } else {
        setup_misc<<<26, 256, 0, stream>>>(Kone, Kb + GQ, Vt + GQ);
        qkv_gemm_f32<<<1176, 256, 0, stream>>>(hs, qkv_w, qkv_b, Qb, Kb, Vt);
        flash_attn<<<1600, 256, 0, stream>>>(Qb, Kb, Vt, rph, rpw, Kone, AO);
        proj_gemm_f32<<<392, 256, 0, stream>>>(AO, proj_w, proj_b, out);
    }
}

// Round 8
// 292.057 us; speedup vs baseline: 1.6416x; 1.6416x over previous
//
#include <hip/hip_runtime.h>
#include <hip/hip_bf16.h>
#include <stdint.h>

typedef __bf16 bf16;
typedef __bf16 bf16x2 __attribute__((ext_vector_type(2)));
typedef __bf16 bf16x4 __attribute__((ext_vector_type(4)));
typedef __bf16 bf16x8 __attribute__((ext_vector_type(8)));
typedef float f32x4 __attribute__((ext_vector_type(4)));

#define AS1 __attribute__((address_space(1)))
#define AS3 __attribute__((address_space(3)))

static __device__ __forceinline__ void async_cp16(const bf16* g, bf16* l) {
    __builtin_amdgcn_global_load_lds((const AS1 void*)g, (AS3 void*)l, 16, 0, 0);
}

static __device__ __forceinline__ bf16x4 cvt4(f32x4 v) {
    bf16x4 r;
    r[0] = (bf16)v[0]; r[1] = (bf16)v[1]; r[2] = (bf16)v[2]; r[3] = (bf16)v[3];
    return r;
}

static __device__ __forceinline__ float fast_exp2(float x) {
#if __has_builtin(__builtin_amdgcn_exp2f)
    return __builtin_amdgcn_exp2f(x);
#else
    return __expf(x * 0.69314718056f);
#endif
}

// ---------------------------------------------------------------------------
// prep_kernel: fused {Kone one-hot build + slack zeroing} + fp32->bf16 bulk
// convert of hs/qkv_w/proj_w (dsts contiguous in ws).
__global__ __launch_bounds__(256) void prep_kernel(
    const float* __restrict__ hs, const float* __restrict__ qw,
    const float* __restrict__ pw, bf16* __restrict__ dst,
    bf16* __restrict__ Kone, bf16* __restrict__ slackA, bf16* __restrict__ slackB) {
    const int gid = blockIdx.x * 256 + threadIdx.x;
    // part 1: Kone [1600][32]: dim j<28: j==27-wk; dim 28+jj: jj==3-(hk-ha)
    if (gid < 6400) {
        const int key = gid >> 2, chunk = gid & 3;
        const int hk = key / 28;
        const int wk = key - hk * 28;
        const int kt = key >> 6;
        const int ha = (kt << 6) / 28;
        const int jw = 27 - wk;
        const int jh = 31 - (hk - ha);
        bf16x8 v;
#pragma unroll
        for (int e = 0; e < 8; e++) {
            const int j = chunk * 8 + e;
            v[e] = (j == jw || j == jh) ? (bf16)1.0f : (bf16)0.0f;
        }
        *(bf16x8*)&Kone[key * 32 + chunk * 8] = v;
    } else if (gid < 6656) {
        const int i = gid - 6400;   // 2048 slack elems after Kb and Vt
        bf16x8 z = {};
        *(bf16x8*)&slackA[i * 8] = z;
        *(bf16x8*)&slackB[i * 8] = z;
    }
    // part 2: grid-stride cvt
    const int H4 = 6272 * 1024 / 4, Q4 = 3072 * 1024 / 4, P4 = 1024 * 1024 / 4;
    const int total = H4 + Q4 + P4;
    const int stride = gridDim.x * 256;
    for (int i = gid; i < total; i += stride) {
        f32x4 v;
        if (i < H4)            v = ((const f32x4*)hs)[i];
        else if (i < H4 + Q4)  v = ((const f32x4*)qw)[i - H4];
        else                   v = ((const f32x4*)pw)[i - H4 - Q4];
        ((bf16x4*)dst)[i] = cvt4(v);
    }
}

// setup-only kernel for the f32 fallback path (no cvt needed there).
__global__ __launch_bounds__(256) void setup_misc(
    bf16* __restrict__ Kone, bf16* __restrict__ slackA, bf16* __restrict__ slackB) {
    const int idx = blockIdx.x * 256 + threadIdx.x;
    if (idx < 6400) {
        const int key = idx >> 2, chunk = idx & 3;
        const int hk = key / 28;
        const int wk = key - hk * 28;
        const int kt = key >> 6;
        const int ha = (kt << 6) / 28;
        const int jw = 27 - wk;
        const int jh = 31 - (hk - ha);
        bf16x8 v;
#pragma unroll
        for (int e = 0; e < 8; e++) {
            const int j = chunk * 8 + e;
            v[e] = (j == jw || j == jh) ? (bf16)1.0f : (bf16)0.0f;
        }
        *(bf16x8*)&Kone[key * 32 + chunk * 8] = v;
    } else if (idx < 6656) {
        const int i = idx - 6400;
        bf16x8 z = {};
        *(bf16x8*)&slackA[i * 8] = z;
        *(bf16x8*)&slackB[i * 8] = z;
    }
}

// NOTE: epilogue is INLINED in both qkv kernels. An earlier round passed
// acc[4][4] into a helper; array-decay defeated SROA -> acc lived in scratch.
// Do not refactor accumulators through pointers.
//
// NOTE (round 7): __launch_bounds__(256,5) forced VGPR to 48 -> full spill,
// WRITE_SIZE 43->424 MB, qkv 100->244 us. The acc live-set needs ~112 VGPR;
// do NOT add a min-waves bound to these GEMMs.
//
// Q is pre-scaled by C2 = 0.125*log2(e) here so flash_attn's QK MFMA output
// is already in the exp2 domain (the rel-pos tables compensate with *8).

#define QKV_EPILOGUE()                                                        \
    for (int nt = 0; nt < 4; nt++) {                                          \
        const int n_ = n0 + wn + nt * 16 + lm;                                \
        const float bv = bias[n_];                                            \
        const int s = n_ >> 10, rem = n_ & 1023;                              \
        const int h = rem >> 6, d = rem & 63;                                 \
        const float qsc = (s == 0) ? 0.18033688011112042f : 1.0f;             \
        for (int mt = 0; mt < 4; mt++) {                                      \
            for (int r = 0; r < 4; r++) {                                     \
                const int m_ = m0 + wm + mt * 16 + quad * 4 + r;              \
                const int b = m_ / 1568;                                      \
                const int pix = m_ - b * 1568;                                \
                const int g = b * 16 + h;                                     \
                const bf16 v = (bf16)((acc[mt][nt][r] + bv) * qsc);           \
                if (s == 0)      Qb[((size_t)g * 1568 + pix) * 64 + d] = v;   \
                else if (s == 1) Kb[((size_t)g * 1568 + pix) * 64 + d] = v;   \
                else {                                                        \
                    const int lk = pix & 31;                                  \
                    const int ppix = (pix & ~31) | ((lk & 15) << 1) | (lk >> 4); \
                    Vt[((size_t)g * 64 + d) * 1568 + ppix] = v;               \
                }                                                             \
            }                                                                 \
        }                                                                     \
    }

// Round-5 proven structure: 2-buffer dbuf, __syncthreads per tile. Latency
// hiding comes from BLOCK-level TLP (round-6: deeper pipeline traded LDS for
// TLP and regressed; round-7: forcing occupancy via launch_bounds spilled).

// ---------------------------------------------------------------------------
// Kernel 1a: QKV projection, bf16 inputs, XCD-chunked swizzle (1176 blocks).
__global__ __launch_bounds__(256) void qkv_gemm_bf16(
    const bf16* __restrict__ A, const bf16* __restrict__ W,
    const float* __restrict__ bias, bf16* __restrict__ Qb,
    bf16* __restrict__ Kb, bf16* __restrict__ Vt) {
    __shared__ bf16 As[2][128 * 32];
    __shared__ bf16 Bs[2][128 * 32];
    const int t = threadIdx.x;
    const int wid = t >> 6, lane = t & 63;
    const int bid = blockIdx.x;
    const int widx = (bid & 7) * 147 + (bid >> 3);
    const int mt_ = widx / 24;
    const int m0 = mt_ * 128, n0 = (widx - mt_ * 24) * 128;
    const int wm = (wid & 1) * 64, wn = (wid >> 1) * 64;
    const int r_i = lane >> 2, c8 = (lane & 3) * 8;
    const int lm = lane & 15, quad = lane >> 4;

#define QKV_STAGE(buf, kk)                                                     \
    for (int i = 0; i < 2; i++) {                                              \
        const int blk = wid * 2 + i;                                           \
        async_cp16(A + (size_t)(m0 + blk * 16 + r_i) * 1024 + (kk) + c8,       \
                   &As[buf][blk * 512]);                                       \
        async_cp16(W + (size_t)(n0 + blk * 16 + r_i) * 1024 + (kk) + c8,       \
                   &Bs[buf][blk * 512]);                                       \
    }

    f32x4 acc[4][4] = {};
    QKV_STAGE(0, 0)
    __syncthreads();
    int cur = 0;
    for (int k0 = 0; k0 < 1024; k0 += 32) {
        if (k0 < 992) { QKV_STAGE(cur ^ 1, k0 + 32) }
        bf16x8 af[4], bfr[4];
        for (int x = 0; x < 4; x++) {
            af[x]  = *(const bf16x8*)&As[cur][(wm + x * 16 + lm) * 32 + quad * 8];
            bfr[x] = *(const bf16x8*)&Bs[cur][(wn + x * 16 + lm) * 32 + quad * 8];
        }
        for (int mt = 0; mt < 4; mt++)
            for (int nt = 0; nt < 4; nt++)
                acc[mt][nt] = __builtin_amdgcn_mfma_f32_16x16x32_bf16(af[mt], bfr[nt], acc[mt][nt], 0, 0, 0);
        __syncthreads();
        cur ^= 1;
    }
#undef QKV_STAGE
    QKV_EPILOGUE()
}

// Kernel 1b: fallback — fp32 inputs, convert at LDS-stage time (dbuf).
__global__ __launch_bounds__(256) void qkv_gemm_f32(
    const float* __restrict__ A, const float* __restrict__ W,
    const float* __restrict__ bias, bf16* __restrict__ Qb,
    bf16* __restrict__ Kb, bf16* __restrict__ Vt) {
    __shared__ bf16 As[2][128 * 32];
    __shared__ bf16 Bs[2][128 * 32];
    const int t = threadIdx.x;
    const int wid = t >> 6, lane = t & 63;
    const int bid = blockIdx.x;
    const int widx = (bid & 7) * 147 + (bid >> 3);
    const int mt_ = widx / 24;
    const int m0 = mt_ * 128, n0 = (widx - mt_ * 24) * 128;
    const int wm = (wid & 1) * 64, wn = (wid >> 1) * 64;
    const int lm = lane & 15, quad = lane >> 4;

#define QKVF_STAGE(buf, kk)                                                    \
    for (int i = 0; i < 4; i++) {                                              \
        const int idx = t + i * 256;                                           \
        const int row = idx >> 3, c4 = (idx & 7) * 4;                          \
        const f32x4 av = *(const f32x4*)&A[(size_t)(m0 + row) * 1024 + (kk) + c4]; \
        const f32x4 wv = *(const f32x4*)&W[(size_t)(n0 + row) * 1024 + (kk) + c4]; \
        *(bf16x4*)&As[buf][row * 32 + c4] = cvt4(av);                          \
        *(bf16x4*)&Bs[buf][row * 32 + c4] = cvt4(wv);                          \
    }

    f32x4 acc[4][4] = {};
    QKVF_STAGE(0, 0)
    __syncthreads();
    int cur = 0;
    for (int k0 = 0; k0 < 1024; k0 += 32) {
        if (k0 < 992) { QKVF_STAGE(cur ^ 1, k0 + 32) }
        bf16x8 af[4], bfr[4];
        for (int x = 0; x < 4; x++) {
            af[x]  = *(const bf16x8*)&As[cur][(wm + x * 16 + lm) * 32 + quad * 8];
            bfr[x] = *(const bf16x8*)&Bs[cur][(wn + x * 16 + lm) * 32 + quad * 8];
        }
        for (int mt = 0; mt < 4; mt++)
            for (int nt = 0; nt < 4; nt++)
                acc[mt][nt] = __builtin_amdgcn_mfma_f32_16x16x32_bf16(af[mt], bfr[nt], acc[mt][nt], 0, 0, 0);
        __syncthreads();
        cur ^= 1;
    }
#undef QKVF_STAGE
    QKV_EPILOGUE()
}

// ---------------------------------------------------------------------------
// Kernel 2: flash attention, KVBLK=64, 25 tiles, ONE barrier per tile.
__global__ __launch_bounds__(256) void flash_attn(
    const bf16* __restrict__ Qb, const bf16* __restrict__ Kb,
    const bf16* __restrict__ Vt, const float* __restrict__ rph,
    const float* __restrict__ rpw, const bf16* __restrict__ Kone,
    bf16* __restrict__ AO) {
    const int x = blockIdx.x;
    const int xcd = x & 7, j = x >> 3;          // j in 0..199
    const int g = xcd * 8 + j / 25;
    const int qblk = j - (j / 25) * 25;
    const int q0 = qblk * 64;
    const int hqb = q0 / 28;                    // first image row of this block

    __shared__ __align__(16) char smem[51200];
    bf16* Th = (bf16*)smem;
    const char* ThC = (const char*)smem;
    char* B = smem + 8192;
    bf16* Qs  = (bf16*)(B + 32768);
    bf16* RPh = (bf16*)(B + 0);
    bf16* RPw = (bf16*)(B + 9216);
    float* TwF = (float*)(B + 18432);
    bf16* TwS = (bf16*)(B + 33280);

    const int t = threadIdx.x, wid = t >> 6, lane = t & 63;
    const int lm = lane & 15, quad = lane >> 4;
    const int qbase_l = wid * 16 + quad * 4;
    const int swz = (lm & 7) << 4;
    const int l3 = lane >> 3, l7 = lane & 7;
    const int swe = ((l7 ^ l3) << 3);           // pre-swizzled source col (elems)

    const bf16* kSrc[2];
    const bf16* vSrc[2];
#pragma unroll
    for (int i = 0; i < 2; i++) {
        kSrc[i] = Kb + ((size_t)g * 1568 + wid * 16 + i * 8 + l3) * 64 + swe;
        vSrc[i] = Vt + ((size_t)g * 64 + wid * 16 + i * 8 + l3) * 1568 + swe;
    }

    // phase 0: stage Q tile (rows clamped for the q tail) + rph
    for (int c = t; c < 512; c += 256) {
        const int row = c >> 3, col = (c & 7) * 8;
        const int qg = min(q0 + row, 1567);
        *(bf16x8*)&Qs[row * 72 + col] =
            *(const bf16x8*)&Qb[((size_t)g * 1568 + qg) * 64 + col];
    }
    for (int c = t; c < 1024; c += 256) {
        const int row = c >> 4, col = (c & 15) * 4;
        const int rg = min(hqb + row, 110);
        *(bf16x4*)&RPh[row * 72 + col] = cvt4(*(const f32x4*)&rph[rg * 64 + col]);
    }
    __syncthreads();

    // phase 1: qf reads, Th MFMA (reads RPh), stage rpw (disjoint region)
    const int qrow_l = wid * 16 + lm;
    const bf16x8 qf0 = *(const bf16x8*)&Qs[qrow_l * 72 + quad * 8];
    const bf16x8 qf1 = *(const bf16x8*)&Qs[qrow_l * 72 + 32 + quad * 8];
    const int qgl = min(q0 + qrow_l, 1567);
    const int thb2 = (qrow_l * 64 + (qgl / 28 - hqb) + 54) * 2;   // byte base

    for (int c = t; c < 1024; c += 256) {
        const int row = c >> 4, col = (c & 15) * 4;
        const int rg = min(row, 54);
        *(bf16x4*)&RPw[row * 72 + col] = cvt4(*(const f32x4*)&rpw[rg * 64 + col]);
    }
    f32x4 acch[4];
#pragma unroll
    for (int nt = 0; nt < 4; nt++) {
        const bf16x8 b0 = *(const bf16x8*)&RPh[(nt * 16 + lm) * 72 + quad * 8];
        const bf16x8 b1 = *(const bf16x8*)&RPh[(nt * 16 + lm) * 72 + 32 + quad * 8];
        f32x4 a = {};
        a = __builtin_amdgcn_mfma_f32_16x16x32_bf16(qf0, b0, a, 0, 0, 0);
        a = __builtin_amdgcn_mfma_f32_16x16x32_bf16(qf1, b1, a, 0, 0, 0);
        acch[nt] = a;
    }
    __syncthreads();

    // phase 2: write Th (bf16, *8, col+2 shift, cols 0..1 zeroed),
    //          Tw MFMA (reads RPw) -> TwF f32
#pragma unroll
    for (int nt = 0; nt < 4; nt++) {
        const int c = nt * 16 + lm;
        if (c < 59) {
#pragma unroll
            for (int r = 0; r < 4; r++)
                Th[(qbase_l + r) * 64 + c + 2] = (bf16)(acch[nt][r] * 8.0f);
        }
    }
    if (lm == 0) {
#pragma unroll
        for (int r = 0; r < 4; r++) {
            Th[(qbase_l + r) * 64 + 0] = (bf16)0.0f;
            Th[(qbase_l + r) * 64 + 1] = (bf16)0.0f;
        }
    }
#pragma unroll
    for (int nt = 0; nt < 4; nt++) {
        const bf16x8 b0 = *(const bf16x8*)&RPw[(nt * 16 + lm) * 72 + quad * 8];
        const bf16x8 b1 = *(const bf16x8*)&RPw[(nt * 16 + lm) * 72 + 32 + quad * 8];
        f32x4 a = {};
        a = __builtin_amdgcn_mfma_f32_16x16x32_bf16(qf0, b0, a, 0, 0, 0);
        a = __builtin_amdgcn_mfma_f32_16x16x32_bf16(qf1, b1, a, 0, 0, 0);
        const int c = nt * 16 + lm;
        if (c < 55) {
#pragma unroll
            for (int r = 0; r < 4; r++)
                TwF[(qbase_l + r) * 58 + c] = a[r] * 8.0f;
        }
    }
    __syncthreads();

    // phase 3: build TwS [64][32] bf16 (per-q-row shifted Tw window)
    {
        const int row = t >> 2, chunk = t & 3;
        const int qg = min(q0 + row, 1567);
        const int wq = qg % 28;
        const float* src = &TwF[row * 58 + wq];
        bf16x8 v;
        if (chunk < 3) {
#pragma unroll
            for (int e = 0; e < 8; e++) v[e] = (bf16)src[chunk * 8 + e];
        } else {
#pragma unroll
            for (int e = 0; e < 4; e++) v[e] = (bf16)src[24 + e];
#pragma unroll
            for (int e = 4; e < 8; e++) v[e] = (bf16)0.0f;
        }
        *(bf16x8*)&TwS[row * 32 + chunk * 8] = v;
    }
    __syncthreads();                             // barrier A

    const bf16x8 qt_mine = *(const bf16x8*)&TwS[qrow_l * 32 + quad * 8];

    // stage tile 0 (async, swizzled source) + load Kone tile 0 into regs
#pragma unroll
    for (int i = 0; i < 2; i++) {
        async_cp16(kSrc[i], (bf16*)(B + (wid * 2 + i) * 1024));
        async_cp16(vSrc[i], (bf16*)(B + 16384 + (wid * 2 + i) * 1024));
        kSrc[i] += 4096;
        vSrc[i] += 64;
    }
    const bf16* kop = Kone + lm * 32 + quad * 8;
    bf16x8 ko[4];
#pragma unroll
    for (int f = 0; f < 4; f++) ko[f] = *(const bf16x8*)(kop + f * 512);
    __syncthreads();                             // barrier B (drains staging)

    f32x4 o[4] = {};
    f32x4 lsum = {};
    const f32x4 zero4 = {};
    bf16x8 ones;
#pragma unroll
    for (int i = 0; i < 8; i++) ones[i] = (bf16)1.0f;

    bf16* P0w = (bf16*)(B + 32768) + wid * 640;
    bf16* P1w = (bf16*)(B + 37888) + wid * 640;

    int curo = 0;
    for (int kt = 0; kt < 25; kt++) {
        // Q' quad3 refresh: 4-value Th window (bf16, wave-own rows)
        bf16x8 qf2 = qt_mine;
        if (quad == 3) {
            const int ha = (kt << 6) / 28;
            const char* tp = ThC + (thb2 - (ha << 1));
            qf2[4] = *(const bf16*)(tp);
            qf2[5] = *(const bf16*)(tp + 2);
            qf2[6] = *(const bf16*)(tp + 4);
            qf2[7] = *(const bf16*)(tp + 6);
        }

        // stage tile kt+1 into buf[cur^1] (async; sources pre-swizzled)
        if (kt < 24) {
            const int nxto = curo ^ 8192;
#pragma unroll
            for (int i = 0; i < 2; i++) {
                async_cp16(kSrc[i], (bf16*)(B + nxto + (wid * 2 + i) * 1024));
                async_cp16(vSrc[i], (bf16*)(B + 16384 + nxto + (wid * 2 + i) * 1024));
                kSrc[i] += 4096;
                vSrc[i] += 64;
            }
        }

        // S = bias (one-hot MFMA, C=0) + QK^T
        __builtin_amdgcn_s_setprio(1);
        f32x4 s[4];
#pragma unroll
        for (int f = 0; f < 4; f++)
            s[f] = __builtin_amdgcn_mfma_f32_16x16x32_bf16(qf2, ko[f], zero4, 0, 0, 0);
        {
            const char* KsB = B + curo;
            const int x0 = (quad * 16) ^ swz;
#pragma unroll
            for (int f = 0; f < 4; f++) {
                const char* rp = KsB + (f * 16 + lm) * 128;
                const bf16x8 ka = *(const bf16x8*)(rp + x0);
                const bf16x8 kb2 = *(const bf16x8*)(rp + (x0 ^ 64));
                s[f] = __builtin_amdgcn_mfma_f32_16x16x32_bf16(qf0, ka, s[f], 0, 0, 0);
                s[f] = __builtin_amdgcn_mfma_f32_16x16x32_bf16(qf1, kb2, s[f], 0, 0, 0);
            }
        }
        __builtin_amdgcn_s_setprio(0);

        // reload Kone fragments for the next tile (L1-hot, a whole PV of cover)
        if (kt < 24) {
            kop += 2048;
#pragma unroll
            for (int f = 0; f < 4; f++) ko[f] = *(const bf16x8*)(kop + f * 512);
        }

        if (kt == 24) {                          // keys >= 1568: p == 0
#pragma unroll
            for (int r = 0; r < 4; r++) { s[2][r] = -30000.0f; s[3][r] = -30000.0f; }
        }

        // exp2 + both P halves written, ONE wait, then lsum + PV
#pragma unroll
        for (int r = 0; r < 4; r++) {
            const float a0 = fast_exp2(s[0][r]);
            const float a1 = fast_exp2(s[1][r]);
            bf16x2 pp; pp[0] = (bf16)a0; pp[1] = (bf16)a1;
            *(bf16x2*)&P0w[(quad * 4 + r) * 40 + lm * 2] = pp;
            const float b0 = fast_exp2(s[2][r]);
            const float b1 = fast_exp2(s[3][r]);
            bf16x2 qq; qq[0] = (bf16)b0; qq[1] = (bf16)b1;
            *(bf16x2*)&P1w[(quad * 4 + r) * 40 + lm * 2] = qq;
        }
        __asm__ volatile("s_waitcnt lgkmcnt(0)" ::: "memory");
        const bf16x8 pf0 = *(const bf16x8*)&P0w[lm * 40 + quad * 8];
        const bf16x8 pf1 = *(const bf16x8*)&P1w[lm * 40 + quad * 8];
        lsum = __builtin_amdgcn_mfma_f32_16x16x32_bf16(pf0, ones, lsum, 0, 0, 0);
        lsum = __builtin_amdgcn_mfma_f32_16x16x32_bf16(pf1, ones, lsum, 0, 0, 0);
        __builtin_amdgcn_s_setprio(1);
        {
            const char* VsB = B + 16384 + curo;
#pragma unroll
            for (int dt = 0; dt < 4; dt++) {
                const bf16x8 vf = *(const bf16x8*)(VsB + (dt * 16 + lm) * 128 +
                                                   ((quad * 16) ^ swz));
                o[dt] = __builtin_amdgcn_mfma_f32_16x16x32_bf16(pf0, vf, o[dt], 0, 0, 0);
            }
#pragma unroll
            for (int dt = 0; dt < 4; dt++) {
                const bf16x8 vf = *(const bf16x8*)(VsB + (dt * 16 + lm) * 128 +
                                                   ((64 + quad * 16) ^ swz));
                o[dt] = __builtin_amdgcn_mfma_f32_16x16x32_bf16(pf1, vf, o[dt], 0, 0, 0);
            }
        }
        __builtin_amdgcn_s_setprio(0);

        if (kt < 24) {                           // uniform: one barrier per tile
            __syncthreads();
            curo ^= 8192;
        }
    }

    // epilogue: lsum already holds per-row softmax denominators (no shuffle)
    if (q0 + wid * 16 < 1568) {
        const int bo = g >> 4, hh = g & 15;
#pragma unroll
        for (int r = 0; r < 4; r++) {
            const float inv = 1.0f / lsum[r];
            const size_t base = ((size_t)bo * 1568 + q0 + qbase_l + r) * 1024 + hh * 64;
#pragma unroll
            for (int dt = 0; dt < 4; dt++)
                AO[base + dt * 16 + lm] = (bf16)(o[dt][r] * inv);
        }
    }
}

// ---------------------------------------------------------------------------
// Kernel 3a: output projection, bf16 operands, XCD swizzle, dbuf K-loop.
__global__ __launch_bounds__(256) void proj_gemm_bf16(
    const bf16* __restrict__ A, const bf16* __restrict__ W,
    const float* __restrict__ bias, float* __restrict__ out) {
    __shared__ bf16 As[2][128 * 32];
    __shared__ bf16 Bs[2][128 * 32];
    const int t = threadIdx.x;
    const int wid = t >> 6, lane = t & 63;
    const int bid = blockIdx.x;
    const int widx = (bid & 7) * 49 + (bid >> 3);
    const int m0 = (widx >> 3) * 128, n0 = (widx & 7) * 128;
    const int wm = (wid & 1) * 64, wn = (wid >> 1) * 64;
    const int r_i = lane >> 2, c8 = (lane & 3) * 8;
    const int lm = lane & 15, quad = lane >> 4;

#define PROJ_STAGE(buf, kk)                                                    \
    for (int i = 0; i < 2; i++) {                                              \
        const int blk = wid * 2 + i;                                           \
        async_cp16(A + (size_t)(m0 + blk * 16 + r_i) * 1024 + (kk) + c8,       \
                   &As[buf][blk * 512]);                                       \
        async_cp16(W + (size_t)(n0 + blk * 16 + r_i) * 1024 + (kk) + c8,       \
                   &Bs[buf][blk * 512]);                                       \
    }

    f32x4 acc[4][4] = {};
    PROJ_STAGE(0, 0)
    __syncthreads();
    int cur = 0;
    for (int k0 = 0; k0 < 1024; k0 += 32) {
        if (k0 < 992) { PROJ_STAGE(cur ^ 1, k0 + 32) }
        bf16x8 af[4], bfr[4];
        for (int x = 0; x < 4; x++) {
            af[x]  = *(const bf16x8*)&As[cur][(wm + x * 16 + lm) * 32 + quad * 8];
            bfr[x] = *(const bf16x8*)&Bs[cur][(wn + x * 16 + lm) * 32 + quad * 8];
        }
        for (int mt = 0; mt < 4; mt++)
            for (int nt = 0; nt < 4; nt++)
                acc[mt][nt] = __builtin_amdgcn_mfma_f32_16x16x32_bf16(af[mt], bfr[nt], acc[mt][nt], 0, 0, 0);
        __syncthreads();
        cur ^= 1;
    }
#undef PROJ_STAGE
    for (int nt = 0; nt < 4; nt++) {
        const int n_ = n0 + wn + nt * 16 + lm;
        const float bv = bias[n_];
        for (int mt = 0; mt < 4; mt++)
            for (int r = 0; r < 4; r++) {
                const int m_ = m0 + wm + mt * 16 + quad * 4 + r;
                out[(size_t)m_ * 1024 + n_] = acc[mt][nt][r] + bv;
            }
    }
}

// Kernel 3b: fallback — W fp32, converted at stage time (dbuf).
__global__ __launch_bounds__(256) void proj_gemm_f32(
    const bf16* __restrict__ A, const float* __restrict__ W,
    const float* __restrict__ bias, float* __restrict__ out) {
    __shared__ bf16 As[2][128 * 32];
    __shared__ bf16 Bs[2][128 * 32];
    const int t = threadIdx.x;
    const int wid = t >> 6, lane = t & 63;
    const int bid = blockIdx.x;
    const int widx = (bid & 7) * 49 + (bid >> 3);
    const int m0 = (widx >> 3) * 128, n0 = (widx & 7) * 128;
    const int wm = (wid & 1) * 64, wn = (wid >> 1) * 64;
    const int r_i = lane >> 2, c8 = (lane & 3) * 8;
    const int lm = lane & 15, quad = lane >> 4;

#define PROJF_STAGE(buf, kk)                                                   \
    for (int i = 0; i < 2; i++) {                                              \
        const int blk = wid * 2 + i;                                           \
        async_cp16(A + (size_t)(m0 + blk * 16 + r_i) * 1024 + (kk) + c8,       \
                   &As[buf][blk * 512]);                                       \
    }                                                                          \
    for (int i = 0; i < 4; i++) {                                              \
        const int idx = t + i * 256;                                           \
        const int row = idx >> 3, c4 = (idx & 7) * 4;                          \
        const f32x4 wv = *(const f32x4*)&W[(size_t)(n0 + row) * 1024 + (kk) + c4]; \
        *(bf16x4*)&Bs[buf][row * 32 + c4] = cvt4(wv);                          \
    }

    f32x4 acc[4][4] = {};
    PROJF_STAGE(0, 0)
    __syncthreads();
    int cur = 0;
    for (int k0 = 0; k0 < 1024; k0 += 32) {
        if (k0 < 992) { PROJF_STAGE(cur ^ 1, k0 + 32) }
        bf16x8 af[4], bfr[4];
        for (int x = 0; x < 4; x++) {
            af[x]  = *(const bf16x8*)&As[cur][(wm + x * 16 + lm) * 32 + quad * 8];
            bfr[x] = *(const bf16x8*)&Bs[cur][(wn + x * 16 + lm) * 32 + quad * 8];
        }
        for (int mt = 0; mt < 4; mt++)
            for (int nt = 0; nt < 4; nt++)
                acc[mt][nt] = __builtin_amdgcn_mfma_f32_16x16x32_bf16(af[mt], bfr[nt], acc[mt][nt], 0, 0, 0);
        __syncthreads();
        cur ^= 1;
    }
#undef PROJF_STAGE
    for (int nt = 0; nt < 4; nt++) {
        const int n_ = n0 + wn + nt * 16 + lm;
        const float bv = bias[n_];
        for (int mt = 0; mt < 4; mt++)
            for (int r = 0; r < 4; r++) {
                const int m_ = m0 + wm + mt * 16 + quad * 4 + r;
                out[(size_t)m_ * 1024 + n_] = acc[mt][nt][r] + bv;
            }
    }
}

// ---------------------------------------------------------------------------
extern "C" void kernel_launch(void* const* d_in, const int* in_sizes, int n_in,
                              void* d_out, int out_size, void* d_ws, size_t ws_size,
                              hipStream_t stream) {
    const float* hs     = (const float*)d_in[0];
    const float* qkv_w  = (const float*)d_in[1];
    const float* qkv_b  = (const float*)d_in[2];
    const float* proj_w = (const float*)d_in[3];
    const float* proj_b = (const float*)d_in[4];
    const float* rph    = (const float*)d_in[5];
    const float* rpw    = (const float*)d_in[6];
    float* out = (float*)d_out;

    const size_t GQ  = (size_t)64 * 1568 * 64; // elems per Q/K/V/AO
    const size_t SL  = 2048;                   // slack after Kb and Vt
    const size_t N_KONE = (size_t)1600 * 32;
    const size_t N_HS = (size_t)6272 * 1024;
    const size_t N_QW = (size_t)3072 * 1024;
    const size_t N_PW = (size_t)1024 * 1024;
    bf16* Qb = (bf16*)d_ws;                    // [g][1568][64] (pre-scaled by C2)
    bf16* Kb = Qb + GQ;                        // [g][1568][64] + slack
    bf16* Vt = Kb + GQ + SL;                   // [g][64][1568] (permuted) + slack
    bf16* AO = Vt + GQ + SL;                   // [6272][1024]
    bf16* Kone = AO + GQ;                      // [1600][32] one-hot
    bf16* hs_bf    = Kone + N_KONE;            // hs_bf/qkvw_bf/projw_bf contiguous
    bf16* qkvw_bf  = hs_bf + N_HS;
    bf16* projw_bf = qkvw_bf + N_QW;
    const size_t need = (4 * GQ + 2 * SL + N_KONE + N_HS + N_QW + N_PW) * sizeof(bf16);

    if (ws_size >= need) {
        prep_kernel<<<1024, 256, 0, stream>>>(hs, qkv_w, proj_w, hs_bf,
                                              Kone, Kb + GQ, Vt + GQ);
        qkv_gemm_bf16<<<1176, 256, 0, stream>>>(hs_bf, qkvw_bf, qkv_b, Qb, Kb, Vt);
        flash_attn<<<1600, 256, 0, stream>>>(Qb, Kb, Vt, rph, rpw, Kone, AO);
        proj_gemm_bf16<<<392, 256, 0, stream>>>(AO, projw_bf, proj_b, out);
    } else {
        setup_misc<<<26, 256, 0, stream>>>(Kone, Kb + GQ, Vt + GQ);
        qkv_gemm_f32<<<1176, 256, 0, stream>>>(hs, qkv_w, qkv_b, Qb, Kb, Vt);
        flash_attn<<<1600, 256, 0, stream>>>(Qb, Kb, Vt, rph, rpw, Kone, AO);
        proj_gemm_f32<<<392, 256, 0, stream>>>(AO, proj_w, proj_b, out);
    }
}